// Round 1
// baseline (1010.126 us; speedup 1.0000x reference)
//
#include <hip/hip_runtime.h>

// Gated DeltaNet single recurrent step.
//   out[v] = g*qS[v] + (q.k)*beta*(v[v] - g*kS[v])
//   qS[v] = sum_k q[k]*S[k][v],  kS[v] = sum_k k[k]*S[k][v]
// B=256, H=48, DK=DV=128. P = B*H = 12288 pairs.
// One wave per pair; 4 waves (256 threads) per block; grid = P/4 = 3072.
// Memory-bound: one streaming pass over state (805 MB) dominates.

#define DKX 128
#define DVX 128
#define WAVES_PER_BLOCK 4

__global__ __launch_bounds__(256, 4) void gdn_step_kernel(
    const float* __restrict__ q,
    const float* __restrict__ k,
    const float* __restrict__ v,
    const float* __restrict__ beta,
    const float* __restrict__ gate,
    const float* __restrict__ state,
    float* __restrict__ out)
{
    // Interleaved (q[i], k[i]) so the hot loop does one ds_read_b64.
    __shared__ float2 qk_lds[WAVES_PER_BLOCK][DKX];

    const int wave = threadIdx.x >> 6;
    const int lane = threadIdx.x & 63;
    const int p    = blockIdx.x * WAVES_PER_BLOCK + wave;   // (b,h) pair index

    const float* qp = q + (size_t)p * DKX;
    const float* kp = k + (size_t)p * DKX;

    // Stage q,k into LDS (lane l covers i=l and i=l+64).
    {
        float q0 = qp[lane];
        float k0 = kp[lane];
        float q1 = qp[lane + 64];
        float k1 = kp[lane + 64];
        qk_lds[wave][lane]      = make_float2(q0, k0);
        qk_lds[wave][lane + 64] = make_float2(q1, k1);
    }
    __syncthreads();

    // qk = q . k  (butterfly reduce across the wave)
    float qk;
    {
        float2 a = qk_lds[wave][lane];
        float2 b = qk_lds[wave][lane + 64];
        float pa = a.x * a.y + b.x * b.y;
        #pragma unroll
        for (int off = 32; off >= 1; off >>= 1)
            pa += __shfl_xor(pa, off, 64);
        qk = pa;
    }

    // Main streaming pass over S.
    // Lane layout: row parity = lane>>5, columns = (lane&31)*4 .. +3.
    // Each iteration the wave reads 2 full rows = 1 KiB contiguous.
    const int rpar = lane >> 5;
    const int cg4  = (lane & 31) * 4;
    const float* sp = state + (size_t)p * DKX * DVX + (size_t)rpar * DVX + cg4;

    float qs0 = 0.f, qs1 = 0.f, qs2 = 0.f, qs3 = 0.f;
    float ks0 = 0.f, ks1 = 0.f, ks2 = 0.f, ks3 = 0.f;

    #pragma unroll 8
    for (int it = 0; it < DKX / 2; ++it) {
        const int k0 = it * 2 + rpar;
        float2 qkv = qk_lds[wave][k0];              // (q[k0], k[k0])
        float4 s = *(const float4*)(sp + (size_t)it * 2 * DVX);
        qs0 += qkv.x * s.x;  ks0 += qkv.y * s.x;
        qs1 += qkv.x * s.y;  ks1 += qkv.y * s.y;
        qs2 += qkv.x * s.z;  ks2 += qkv.y * s.z;
        qs3 += qkv.x * s.w;  ks3 += qkv.y * s.w;
    }

    // Combine the two half-wave partial sums (lane <-> lane^32 own same cols).
    qs0 += __shfl_xor(qs0, 32, 64);
    qs1 += __shfl_xor(qs1, 32, 64);
    qs2 += __shfl_xor(qs2, 32, 64);
    qs3 += __shfl_xor(qs3, 32, 64);
    ks0 += __shfl_xor(ks0, 32, 64);
    ks1 += __shfl_xor(ks1, 32, 64);
    ks2 += __shfl_xor(ks2, 32, 64);
    ks3 += __shfl_xor(ks3, 32, 64);

    if (lane < 32) {
        const float g  = gate[p];
        const float bt = beta[p];
        const float coeff = qk * bt;

        float4 v4 = *(const float4*)(v + (size_t)p * DVX + cg4);

        float4 o;
        o.x = g * qs0 + coeff * (v4.x - g * ks0);
        o.y = g * qs1 + coeff * (v4.y - g * ks1);
        o.z = g * qs2 + coeff * (v4.z - g * ks2);
        o.w = g * qs3 + coeff * (v4.w - g * ks3);

        *(float4*)(out + (size_t)p * DVX + cg4) = o;
    }
}

extern "C" void kernel_launch(void* const* d_in, const int* in_sizes, int n_in,
                              void* d_out, int out_size, void* d_ws, size_t ws_size,
                              hipStream_t stream) {
    const float* q     = (const float*)d_in[0];
    const float* k     = (const float*)d_in[1];
    const float* v     = (const float*)d_in[2];
    const float* beta  = (const float*)d_in[3];
    const float* gate  = (const float*)d_in[4];
    const float* state = (const float*)d_in[5];
    float* out = (float*)d_out;

    const int P = in_sizes[3];              // B*H = 12288
    const int grid = P / WAVES_PER_BLOCK;   // 3072 blocks
    gdn_step_kernel<<<grid, 64 * WAVES_PER_BLOCK, 0, stream>>>(
        q, k, v, beta, gate, state, out);
}